// Round 2
// baseline (129.017 us; speedup 1.0000x reference)
//
#include <hip/hip_runtime.h>
#include <stdint.h>

#define IN_F 4096
#define OUT_F 11008
#define M_ROWS 256
#define RANK 16
#define NWORDS (IN_F / 16)   // 256 packed words per output row

#define BM 64
#define BN 64
#define BK 64
#define SPLITK 2
#define K_PER (IN_F / SPLITK)   // 2048
#define KT_COUNT (K_PER / BK)   // 32

typedef unsigned short u16;
typedef __attribute__((ext_vector_type(8))) short short8;
typedef __attribute__((ext_vector_type(4))) float floatx4;

__device__ __forceinline__ u16 f32_to_bf16_rne(float f) {
    uint32_t u = __builtin_bit_cast(uint32_t, f);
    uint32_t r = (u + 0x7FFFu + ((u >> 16) & 1u)) >> 16;
    return (u16)r;
}

// ---------------- prep: rowsum, lora_xA, x->bf16 (float4-vectorized) --------
__global__ __launch_bounds__(256) void prep_kernel(
    const float* __restrict__ x, const float* __restrict__ lora_A,
    u16* __restrict__ xb, float* __restrict__ srow, float* __restrict__ lxa)
{
    const int m = blockIdx.x;
    const int tid = threadIdx.x;
    const float4* xrow4 = (const float4*)(x + (size_t)m * IN_F);
    const float4* la4 = (const float4*)lora_A;
    float ssum = 0.f;
    float acc[RANK];
#pragma unroll
    for (int r = 0; r < RANK; ++r) acc[r] = 0.f;
#pragma unroll
    for (int t = 0; t < IN_F / (256 * 4); ++t) {
        int i4 = t * 256 + tid;
        float4 v = xrow4[i4];
        ssum += v.x + v.y + v.z + v.w;
        union { u16 h[4]; uint2 u2; } pk;
        pk.h[0] = f32_to_bf16_rne(v.x);
        pk.h[1] = f32_to_bf16_rne(v.y);
        pk.h[2] = f32_to_bf16_rne(v.z);
        pk.h[3] = f32_to_bf16_rne(v.w);
        *(uint2*)&xb[(size_t)m * IN_F + i4 * 4] = pk.u2;
#pragma unroll
        for (int r = 0; r < RANK; ++r) {
            float4 a = la4[r * (IN_F / 4) + i4];
            acc[r] = fmaf(v.x, a.x, fmaf(v.y, a.y, fmaf(v.z, a.z, fmaf(v.w, a.w, acc[r]))));
        }
    }
#pragma unroll
    for (int off = 32; off > 0; off >>= 1) {
        ssum += __shfl_down(ssum, off, 64);
#pragma unroll
        for (int r = 0; r < RANK; ++r) acc[r] += __shfl_down(acc[r], off, 64);
    }
    __shared__ float red[4][RANK + 1];
    int wv = tid >> 6, ln = tid & 63;
    if (ln == 0) {
        red[wv][0] = ssum;
#pragma unroll
        for (int r = 0; r < RANK; ++r) red[wv][1 + r] = acc[r];
    }
    __syncthreads();
    if (tid == 0) srow[m] = red[0][0] + red[1][0] + red[2][0] + red[3][0];
    if (tid < RANK)
        lxa[m * RANK + tid] = red[0][1 + tid] + red[1][1 + tid] + red[2][1 + tid] + red[3][1 + tid];
}

// ---------------- init: out = bias + mu*rowsum + 2*(lxa . B^T) --------------
__global__ __launch_bounds__(256) void init_kernel(
    const float* __restrict__ alphaUnused, const float* __restrict__ mu,
    const float* __restrict__ bias, const float* __restrict__ lora_B,
    const float* __restrict__ srow, const float* __restrict__ lxa,
    float* __restrict__ out)
{
    const int tid = threadIdx.x;
    const int o = blockIdx.x * 256 + tid;
    const int m0 = blockIdx.y * 32;
    float bi = bias[o];
    float muv = mu[o];
    float Br[RANK];
    const float4* b4 = (const float4*)(lora_B + (size_t)o * RANK);
#pragma unroll
    for (int r4 = 0; r4 < RANK / 4; ++r4) {
        float4 v = b4[r4];
        Br[r4 * 4 + 0] = v.x; Br[r4 * 4 + 1] = v.y;
        Br[r4 * 4 + 2] = v.z; Br[r4 * 4 + 3] = v.w;
    }
    __shared__ float ss[32];
    __shared__ float slx[32][RANK];
    if (tid < 32) ss[tid] = srow[m0 + tid];
    for (int t = tid; t < 32 * RANK; t += 256)
        slx[t >> 4][t & 15] = lxa[(m0 + (t >> 4)) * RANK + (t & 15)];
    __syncthreads();
#pragma unroll 4
    for (int mm = 0; mm < 32; ++mm) {
        float dot = 0.f;
#pragma unroll
        for (int r = 0; r < RANK; ++r) dot = fmaf(slx[mm][r], Br[r], dot);
        out[(size_t)(m0 + mm) * OUT_F + o] = bi + muv * ss[mm] + 2.0f * dot;
    }
}

// ---------------- ternary decode: 8 x 2-bit codes -> 8 bf16 ----------------
// code c: 0 -> -1 (0xBF80), 1 -> 0 (0x0000), 2 -> +1 (0x3F80)
__device__ __forceinline__ short8 decode8(uint32_t h)
{
    uint32_t selA = (h & 0xFu) | ((h & 0xF0u) << 12);
    selA = (selA | (selA << 6)) & 0x03030303u;
    uint32_t h2 = h >> 8;
    uint32_t selB = (h2 & 0xFu) | ((h2 & 0xF0u) << 12);
    selB = (selB | (selB << 6)) & 0x03030303u;
    uint32_t hiA = __builtin_amdgcn_perm(0u, 0x003F00BFu, selA);
    uint32_t loA = __builtin_amdgcn_perm(0u, 0x00800080u, selA);
    uint32_t hiB = __builtin_amdgcn_perm(0u, 0x003F00BFu, selB);
    uint32_t loB = __builtin_amdgcn_perm(0u, 0x00800080u, selB);
    union { uint32_t u[4]; short8 s; } cvt;
    cvt.u[0] = __builtin_amdgcn_perm(hiA, loA, 0x05010400u);
    cvt.u[1] = __builtin_amdgcn_perm(hiA, loA, 0x07030602u);
    cvt.u[2] = __builtin_amdgcn_perm(hiB, loB, 0x05010400u);
    cvt.u[3] = __builtin_amdgcn_perm(hiB, loB, 0x07030602u);
    return cvt.s;
}

// ---------------- main fused GEMM (split-K, atomic combine) ----------------
__global__ __launch_bounds__(256) void gemm_kernel(
    const u16* __restrict__ xb, const uint32_t* __restrict__ Tp,
    const float* __restrict__ alpha, float* __restrict__ out)
{
    __shared__ __align__(16) u16 lds[2][BM * BK];
    const int tid = threadIdx.x;
    const int lane = tid & 63;
    const int wave = tid >> 6;
    const int wm = wave >> 1, wn = wave & 1;
    const int mb = blockIdx.y * BM;
    const int nb = blockIdx.x * BN;
    const int k_base = blockIdx.z * K_PER;
    const int kw_base = blockIdx.z * (K_PER / 16);  // word offset within a row

    // B (ternary) addressing
    const int brow0 = nb + wn * 32 + (lane & 15);
    const int bshift = ((lane >> 4) & 1) * 16;
    const uint32_t* tp0 = Tp + (size_t)brow0 * NWORDS + kw_base + (lane >> 5);
    const uint32_t* tp1 = Tp + (size_t)(brow0 + 16) * NWORDS + kw_base + (lane >> 5);

    floatx4 acc[2][2] = {};

    const int r0 = wm * 32 + (lane & 15);
    const int rxor = r0 & 7;

    auto stage = [&](int buf, int kt) {
        const int k0 = k_base + kt * BK;
#pragma unroll
        for (int j = 0; j < 2; ++j) {
            int q = j * 256 + tid;                // 16B chunk id, 0..511
            int row = q >> 3;
            int cc = q & 7;
            int scc = cc ^ (row & 7);             // inverse-swizzled source
            const u16* src = xb + (size_t)(mb + row) * IN_F + k0 + scc * 8;
            __builtin_amdgcn_global_load_lds(
                (const __attribute__((address_space(1))) void*)src,
                (__attribute__((address_space(3))) void*)(&lds[buf][q * 8]),
                16, 0, 0);
        }
    };

    // prefetch B words for kt=0
    uint32_t bw[2][2];
#pragma unroll
    for (int kk = 0; kk < 2; ++kk) {
        bw[kk][0] = tp0[kk * 2];
        bw[kk][1] = tp1[kk * 2];
    }

    stage(0, 0);
    __syncthreads();

    for (int kt = 0; kt < KT_COUNT; ++kt) {
        const int cur = kt & 1;
        uint32_t nw[2][2] = {{0u, 0u}, {0u, 0u}};
        if (kt + 1 < KT_COUNT) {
#pragma unroll
            for (int kk = 0; kk < 2; ++kk) {
                nw[kk][0] = tp0[(kt + 1) * 4 + kk * 2];
                nw[kk][1] = tp1[(kt + 1) * 4 + kk * 2];
            }
            stage(cur ^ 1, kt + 1);
        }
#pragma unroll
        for (int kk = 0; kk < 2; ++kk) {
            short8 bfrag0 = decode8((bw[kk][0] >> bshift) & 0xFFFFu);
            short8 bfrag1 = decode8((bw[kk][1] >> bshift) & 0xFFFFu);
#pragma unroll
            for (int mt = 0; mt < 2; ++mt) {
                int row = r0 + mt * 16;
                int sc = (kk * 4 + (lane >> 4)) ^ rxor;
                const short8 afrag = *(const short8*)&lds[cur][row * BK + sc * 8];
                acc[mt][0] = __builtin_amdgcn_mfma_f32_16x16x32_bf16(afrag, bfrag0, acc[mt][0], 0, 0, 0);
                acc[mt][1] = __builtin_amdgcn_mfma_f32_16x16x32_bf16(afrag, bfrag1, acc[mt][1], 0, 0, 0);
            }
        }
#pragma unroll
        for (int kk = 0; kk < 2; ++kk) {
            bw[kk][0] = nw[kk][0];
            bw[kk][1] = nw[kk][1];
        }
        __syncthreads();
    }

    // ---- epilogue: atomic add alpha * acc ----
    const int o0 = nb + wn * 32 + (lane & 15);
    const int m0 = mb + wm * 32 + ((lane >> 4) * 4);
    float al[2] = { alpha[o0], alpha[o0 + 16] };
#pragma unroll
    for (int mt = 0; mt < 2; ++mt) {
#pragma unroll
        for (int rg = 0; rg < 4; ++rg) {
            int m = m0 + mt * 16 + rg;
#pragma unroll
            for (int nt = 0; nt < 2; ++nt) {
                atomicAdd(&out[(size_t)m * OUT_F + o0 + nt * 16],
                          al[nt] * acc[mt][nt][rg]);
            }
        }
    }
}

extern "C" void kernel_launch(void* const* d_in, const int* in_sizes, int n_in,
                              void* d_out, int out_size, void* d_ws, size_t ws_size,
                              hipStream_t stream)
{
    const float* x = (const float*)d_in[0];
    const uint32_t* Tp = (const uint32_t*)d_in[1];
    const float* alpha = (const float*)d_in[2];
    const float* mu = (const float*)d_in[3];
    const float* bias = (const float*)d_in[4];
    const float* lora_A = (const float*)d_in[5];
    const float* lora_B = (const float*)d_in[6];
    float* out = (float*)d_out;

    u16* xb = (u16*)d_ws;
    float* srow = (float*)((char*)d_ws + (size_t)M_ROWS * IN_F * 2);
    float* lxa = (float*)((char*)d_ws + (size_t)M_ROWS * IN_F * 2 + 4096);

    prep_kernel<<<dim3(M_ROWS), dim3(256), 0, stream>>>(x, lora_A, xb, srow, lxa);
    init_kernel<<<dim3(OUT_F / 256, M_ROWS / 32), dim3(256), 0, stream>>>(
        alpha, mu, bias, lora_B, srow, lxa, out);
    gemm_kernel<<<dim3(OUT_F / BN, M_ROWS / BM, SPLITK), dim3(256), 0, stream>>>(
        xb, Tp, alpha, out);
}

// Round 4
// 89.921 us; speedup vs baseline: 1.4348x; 1.4348x over previous
//
#include <hip/hip_runtime.h>
#include <stdint.h>

#define IN_F 4096
#define OUT_F 11008
#define M_ROWS 256
#define RANK 16
#define NWORDS (IN_F / 16)   // 256 packed words per output row

#define BM 128
#define BN 128
#define BK 64

typedef unsigned short u16;
typedef __attribute__((ext_vector_type(8))) short short8;
typedef __attribute__((ext_vector_type(4))) float floatx4;

__device__ __forceinline__ u16 f32_to_bf16_rne(float f) {
    uint32_t u = __builtin_bit_cast(uint32_t, f);
    uint32_t r = (u + 0x7FFFu + ((u >> 16) & 1u)) >> 16;
    return (u16)r;
}

// ---------------- prep: rowsum, lora_xA, x->bf16 (float4-vectorized) --------
__global__ __launch_bounds__(256) void prep_kernel(
    const float* __restrict__ x, const float* __restrict__ lora_A,
    u16* __restrict__ xb, float* __restrict__ srow, float* __restrict__ lxa)
{
    const int m = blockIdx.x;
    const int tid = threadIdx.x;
    const float4* xrow4 = (const float4*)(x + (size_t)m * IN_F);
    const float4* la4 = (const float4*)lora_A;
    float ssum = 0.f;
    float acc[RANK];
#pragma unroll
    for (int r = 0; r < RANK; ++r) acc[r] = 0.f;
#pragma unroll
    for (int t = 0; t < IN_F / (256 * 4); ++t) {
        int i4 = t * 256 + tid;
        float4 v = xrow4[i4];
        ssum += v.x + v.y + v.z + v.w;
        union { u16 h[4]; uint2 u2; } pk;
        pk.h[0] = f32_to_bf16_rne(v.x);
        pk.h[1] = f32_to_bf16_rne(v.y);
        pk.h[2] = f32_to_bf16_rne(v.z);
        pk.h[3] = f32_to_bf16_rne(v.w);
        *(uint2*)&xb[(size_t)m * IN_F + i4 * 4] = pk.u2;
#pragma unroll
        for (int r = 0; r < RANK; ++r) {
            float4 a = la4[r * (IN_F / 4) + i4];
            acc[r] = fmaf(v.x, a.x, fmaf(v.y, a.y, fmaf(v.z, a.z, fmaf(v.w, a.w, acc[r]))));
        }
    }
#pragma unroll
    for (int off = 32; off > 0; off >>= 1) {
        ssum += __shfl_down(ssum, off, 64);
#pragma unroll
        for (int r = 0; r < RANK; ++r) acc[r] += __shfl_down(acc[r], off, 64);
    }
    __shared__ float red[4][RANK + 1];
    int wv = tid >> 6, ln = tid & 63;
    if (ln == 0) {
        red[wv][0] = ssum;
#pragma unroll
        for (int r = 0; r < RANK; ++r) red[wv][1 + r] = acc[r];
    }
    __syncthreads();
    if (tid == 0) srow[m] = red[0][0] + red[1][0] + red[2][0] + red[3][0];
    if (tid < RANK)
        lxa[m * RANK + tid] = red[0][1 + tid] + red[1][1 + tid] + red[2][1 + tid] + red[3][1 + tid];
}

// ---------------- init: out = bias + mu*rowsum + 2*(lxa . B^T) --------------
__global__ __launch_bounds__(256) void init_kernel(
    const float* __restrict__ mu,
    const float* __restrict__ bias, const float* __restrict__ lora_B,
    const float* __restrict__ srow, const float* __restrict__ lxa,
    float* __restrict__ out)
{
    const int tid = threadIdx.x;
    const int o = blockIdx.x * 256 + tid;
    const int m0 = blockIdx.y * 32;
    float bi = bias[o];
    float muv = mu[o];
    float Br[RANK];
    const float4* b4 = (const float4*)(lora_B + (size_t)o * RANK);
#pragma unroll
    for (int r4 = 0; r4 < RANK / 4; ++r4) {
        float4 v = b4[r4];
        Br[r4 * 4 + 0] = v.x; Br[r4 * 4 + 1] = v.y;
        Br[r4 * 4 + 2] = v.z; Br[r4 * 4 + 3] = v.w;
    }
    __shared__ float ss[32];
    __shared__ float slx[32][RANK];
    if (tid < 32) ss[tid] = srow[m0 + tid];
    for (int t = tid; t < 32 * RANK; t += 256)
        slx[t >> 4][t & 15] = lxa[(m0 + (t >> 4)) * RANK + (t & 15)];
    __syncthreads();
#pragma unroll 4
    for (int mm = 0; mm < 32; ++mm) {
        float dot = 0.f;
#pragma unroll
        for (int r = 0; r < RANK; ++r) dot = fmaf(slx[mm][r], Br[r], dot);
        out[(size_t)(m0 + mm) * OUT_F + o] = bi + muv * ss[mm] + 2.0f * dot;
    }
}

// ---------------- ternary decode: 8 x 2-bit codes -> 8 bf16 ----------------
// VERIFIED (R1/R2): OR-based spread, no carries.
// code c: 0 -> -1 (0xBF80), 1 -> 0 (0x0000), 2 -> +1 (0x3F80)
__device__ __forceinline__ short8 decode8(uint32_t h)
{
    uint32_t selA = (h & 0xFu) | ((h & 0xF0u) << 12);
    selA = (selA | (selA << 6)) & 0x03030303u;
    uint32_t h2 = h >> 8;
    uint32_t selB = (h2 & 0xFu) | ((h2 & 0xF0u) << 12);
    selB = (selB | (selB << 6)) & 0x03030303u;
    uint32_t hiA = __builtin_amdgcn_perm(0u, 0x003F00BFu, selA);
    uint32_t loA = __builtin_amdgcn_perm(0u, 0x00800080u, selA);
    uint32_t hiB = __builtin_amdgcn_perm(0u, 0x003F00BFu, selB);
    uint32_t loB = __builtin_amdgcn_perm(0u, 0x00800080u, selB);
    union { uint32_t u[4]; short8 s; } cvt;
    cvt.u[0] = __builtin_amdgcn_perm(hiA, loA, 0x05010400u);
    cvt.u[1] = __builtin_amdgcn_perm(hiA, loA, 0x07030602u);
    cvt.u[2] = __builtin_amdgcn_perm(hiB, loB, 0x05010400u);
    cvt.u[3] = __builtin_amdgcn_perm(hiB, loB, 0x07030602u);
    return cvt.s;
}

#define WAITV10 asm volatile("s_waitcnt vmcnt(10)" ::: "memory")
#define WAITV5  asm volatile("s_waitcnt vmcnt(5)" ::: "memory")
#define WAITV0  asm volatile("s_waitcnt vmcnt(0)" ::: "memory")

// ------- main fused GEMM: 3-deep pipeline, counted vmcnt, raw barriers -----
__global__ __launch_bounds__(256, 2) void gemm_kernel(
    const u16* __restrict__ xb, const uint32_t* __restrict__ Tp,
    const float* __restrict__ alpha, float* __restrict__ out)
{
    __shared__ __align__(16) u16 ldsA[3][BM * BK];
    __shared__ __align__(16) uint32_t ldsB[3][BN * 4];

    const int tid = threadIdx.x;
    const int lane = tid & 63;
    const int wave = tid >> 6;
    const int wm = wave >> 1, wn = wave & 1;
    const int mb = blockIdx.y * BM;
    const int nb = blockIdx.x * BN;
    const int z = blockIdx.z;
    const int it0 = (z == 0) ? 0 : 22 + 21 * (z - 1);
    const int nit = (z == 0) ? 22 : 21;     // 22+21+21 = 64 K-iterations total

    const int bshift = ((lane >> 4) & 1) * 16;

    // A-stage: 1024 x 16B chunks; 4 per thread; XOR-swizzled SOURCE, linear dest
    const u16* asrc[4];
    int adst[4];
#pragma unroll
    for (int j = 0; j < 4; ++j) {
        int q = j * 256 + tid;
        int row = q >> 3;            // 8 chunks per 64-elem row
        int scc = (q & 7) ^ (row & 7);
        asrc[j] = xb + (size_t)(mb + row) * IN_F + scc * 8;
        adst[j] = q * 8;             // u16 elements
    }
    // B-stage: 128 x 16B chunks (4 words/row); threads 128..255 mirror 0..127
    const int bc = tid & 127;
    const uint32_t* bsrc = Tp + (size_t)(nb + bc) * NWORDS;
    const int bdst = bc * 4;         // u32 elements

    floatx4 acc[4][4] = {};

    auto stage = [&](int buf, int git) {
        const int k0 = git * BK;
#pragma unroll
        for (int j = 0; j < 4; ++j) {
            __builtin_amdgcn_global_load_lds(
                (const __attribute__((address_space(1))) void*)(asrc[j] + k0),
                (__attribute__((address_space(3))) void*)(&ldsA[buf][adst[j]]),
                16, 0, 0);
        }
        __builtin_amdgcn_global_load_lds(
            (const __attribute__((address_space(1))) void*)(bsrc + git * 4),
            (__attribute__((address_space(3))) void*)(&ldsB[buf][bdst]),
            16, 0, 0);
    };

    // body: assumes top-of-iter vmcnt+barrier already done
    auto body = [&](int buf, int git_next, bool do_stage) {
        short8 af[4][2];
        uint32_t bwd[4][2];
#pragma unroll
        for (int mt = 0; mt < 4; ++mt) {
            int r = wm * 64 + mt * 16 + (lane & 15);
#pragma unroll
            for (int kk = 0; kk < 2; ++kk) {
                int sc = kk * 4 + (lane >> 4);
                int chunk = r * 8 + (sc ^ (r & 7));
                af[mt][kk] = *(const short8*)&ldsA[buf][chunk * 8];
            }
        }
#pragma unroll
        for (int nt = 0; nt < 4; ++nt) {
            int row = wn * 64 + nt * 16 + (lane & 15);
#pragma unroll
            for (int kk = 0; kk < 2; ++kk)
                bwd[nt][kk] = ldsB[buf][row * 4 + kk * 2 + (lane >> 5)];
        }
        asm volatile("s_waitcnt lgkmcnt(0)" ::: "memory");
        __builtin_amdgcn_sched_barrier(0);
        __builtin_amdgcn_s_barrier();          // all waves done reading buf
        if (do_stage) stage(buf, git_next);    // overwrite freed buffer
        __builtin_amdgcn_sched_barrier(0);     // pin stage issue before MFMA
        __builtin_amdgcn_s_setprio(1);
#pragma unroll
        for (int kk = 0; kk < 2; ++kk) {
            short8 bf[4];
#pragma unroll
            for (int nt = 0; nt < 4; ++nt)
                bf[nt] = decode8((bwd[nt][kk] >> bshift) & 0xFFFFu);
#pragma unroll
            for (int mt = 0; mt < 4; ++mt)
#pragma unroll
                for (int nt = 0; nt < 4; ++nt)
                    acc[mt][nt] = __builtin_amdgcn_mfma_f32_16x16x32_bf16(
                        af[mt][kk], bf[nt], acc[mt][nt], 0, 0, 0);
        }
        __builtin_amdgcn_s_setprio(0);
    };

    // prologue: fill 3 buffers (15 loads per thread)
    stage(0, it0);
    stage(1, it0 + 1);
    stage(2, it0 + 2);

    int buf = 0;
    for (int j = 0; j < nit - 3; ++j) {
        WAITV10;                               // stage(j) done; j+1,j+2 in flight
        __builtin_amdgcn_s_barrier();
        body(buf, it0 + j + 3, true);
        buf = (buf == 2) ? 0 : buf + 1;
    }
    WAITV10; __builtin_amdgcn_s_barrier();
    body(buf, 0, false);
    buf = (buf == 2) ? 0 : buf + 1;
    WAITV5; __builtin_amdgcn_s_barrier();
    body(buf, 0, false);
    buf = (buf == 2) ? 0 : buf + 1;
    WAITV0; __builtin_amdgcn_s_barrier();
    body(buf, 0, false);

    // ---- epilogue: atomic add alpha * acc onto init values ----
    const int o0 = nb + wn * 64 + (lane & 15);
    const int m0 = mb + wm * 64 + ((lane >> 4) * 4);
    float al[4];
#pragma unroll
    for (int nt = 0; nt < 4; ++nt) al[nt] = alpha[o0 + nt * 16];
#pragma unroll
    for (int mt = 0; mt < 4; ++mt) {
#pragma unroll
        for (int rg = 0; rg < 4; ++rg) {
            int m = m0 + mt * 16 + rg;
#pragma unroll
            for (int nt = 0; nt < 4; ++nt) {
                atomicAdd(&out[(size_t)m * OUT_F + o0 + nt * 16],
                          al[nt] * acc[mt][nt][rg]);
            }
        }
    }
}

extern "C" void kernel_launch(void* const* d_in, const int* in_sizes, int n_in,
                              void* d_out, int out_size, void* d_ws, size_t ws_size,
                              hipStream_t stream)
{
    const float* x = (const float*)d_in[0];
    const uint32_t* Tp = (const uint32_t*)d_in[1];
    const float* alpha = (const float*)d_in[2];
    const float* mu = (const float*)d_in[3];
    const float* bias = (const float*)d_in[4];
    const float* lora_A = (const float*)d_in[5];
    const float* lora_B = (const float*)d_in[6];
    float* out = (float*)d_out;

    u16* xb = (u16*)d_ws;
    float* srow = (float*)((char*)d_ws + (size_t)M_ROWS * IN_F * 2);
    float* lxa = (float*)((char*)d_ws + (size_t)M_ROWS * IN_F * 2 + 4096);

    prep_kernel<<<dim3(M_ROWS), dim3(256), 0, stream>>>(x, lora_A, xb, srow, lxa);
    init_kernel<<<dim3(OUT_F / 256, M_ROWS / 32), dim3(256), 0, stream>>>(
        mu, bias, lora_B, srow, lxa, out);
    gemm_kernel<<<dim3(OUT_F / BN, M_ROWS / BM, 3), dim3(256), 0, stream>>>(
        xb, Tp, alpha, out);
}

// Round 5
// 77.384 us; speedup vs baseline: 1.6672x; 1.1620x over previous
//
#include <hip/hip_runtime.h>
#include <stdint.h>

#define IN_F 4096
#define OUT_F 11008
#define M_ROWS 256
#define RANK 16
#define NWORDS (IN_F / 16)   // 256 packed words per output row

#define BM 64
#define BN 64
#define BK 64
#define NIT (IN_F / BK)      // 64 K-iterations, full K per block

typedef unsigned short u16;
typedef __attribute__((ext_vector_type(8))) short short8;
typedef __attribute__((ext_vector_type(4))) float floatx4;

__device__ __forceinline__ u16 f32_to_bf16_rne(float f) {
    uint32_t u = __builtin_bit_cast(uint32_t, f);
    uint32_t r = (u + 0x7FFFu + ((u >> 16) & 1u)) >> 16;
    return (u16)r;
}

// ---------------- prep: rowsum, lora_xA, x->bf16 (float4-vectorized) --------
__global__ __launch_bounds__(256) void prep_kernel(
    const float* __restrict__ x, const float* __restrict__ lora_A,
    u16* __restrict__ xb, float* __restrict__ srow, float* __restrict__ lxa)
{
    const int m = blockIdx.x;
    const int tid = threadIdx.x;
    const float4* xrow4 = (const float4*)(x + (size_t)m * IN_F);
    const float4* la4 = (const float4*)lora_A;
    float ssum = 0.f;
    float acc[RANK];
#pragma unroll
    for (int r = 0; r < RANK; ++r) acc[r] = 0.f;
#pragma unroll
    for (int t = 0; t < IN_F / (256 * 4); ++t) {
        int i4 = t * 256 + tid;
        float4 v = xrow4[i4];
        ssum += v.x + v.y + v.z + v.w;
        union { u16 h[4]; uint2 u2; } pk;
        pk.h[0] = f32_to_bf16_rne(v.x);
        pk.h[1] = f32_to_bf16_rne(v.y);
        pk.h[2] = f32_to_bf16_rne(v.z);
        pk.h[3] = f32_to_bf16_rne(v.w);
        *(uint2*)&xb[(size_t)m * IN_F + i4 * 4] = pk.u2;
#pragma unroll
        for (int r = 0; r < RANK; ++r) {
            float4 a = la4[r * (IN_F / 4) + i4];
            acc[r] = fmaf(v.x, a.x, fmaf(v.y, a.y, fmaf(v.z, a.z, fmaf(v.w, a.w, acc[r]))));
        }
    }
#pragma unroll
    for (int off = 32; off > 0; off >>= 1) {
        ssum += __shfl_down(ssum, off, 64);
#pragma unroll
        for (int r = 0; r < RANK; ++r) acc[r] += __shfl_down(acc[r], off, 64);
    }
    __shared__ float red[4][RANK + 1];
    int wv = tid >> 6, ln = tid & 63;
    if (ln == 0) {
        red[wv][0] = ssum;
#pragma unroll
        for (int r = 0; r < RANK; ++r) red[wv][1 + r] = acc[r];
    }
    __syncthreads();
    if (tid == 0) srow[m] = red[0][0] + red[1][0] + red[2][0] + red[3][0];
    if (tid < RANK)
        lxa[m * RANK + tid] = red[0][1 + tid] + red[1][1 + tid] + red[2][1 + tid] + red[3][1 + tid];
}

// ---------------- ternary decode: 8 x 2-bit codes -> 8 bf16 ----------------
// VERIFIED (R1/R2/R4): OR-based spread, no carries.
// code c: 0 -> -1 (0xBF80), 1 -> 0 (0x0000), 2 -> +1 (0x3F80)
__device__ __forceinline__ short8 decode8(uint32_t h)
{
    uint32_t selA = (h & 0xFu) | ((h & 0xF0u) << 12);
    selA = (selA | (selA << 6)) & 0x03030303u;
    uint32_t h2 = h >> 8;
    uint32_t selB = (h2 & 0xFu) | ((h2 & 0xF0u) << 12);
    selB = (selB | (selB << 6)) & 0x03030303u;
    uint32_t hiA = __builtin_amdgcn_perm(0u, 0x003F00BFu, selA);
    uint32_t loA = __builtin_amdgcn_perm(0u, 0x00800080u, selA);
    uint32_t hiB = __builtin_amdgcn_perm(0u, 0x003F00BFu, selB);
    uint32_t loB = __builtin_amdgcn_perm(0u, 0x00800080u, selB);
    union { uint32_t u[4]; short8 s; } cvt;
    cvt.u[0] = __builtin_amdgcn_perm(hiA, loA, 0x05010400u);
    cvt.u[1] = __builtin_amdgcn_perm(hiA, loA, 0x07030602u);
    cvt.u[2] = __builtin_amdgcn_perm(hiB, loB, 0x05010400u);
    cvt.u[3] = __builtin_amdgcn_perm(hiB, loB, 0x07030602u);
    return cvt.s;
}

#define WAITV6 asm volatile("s_waitcnt vmcnt(6)" ::: "memory")
#define WAITV3 asm volatile("s_waitcnt vmcnt(3)" ::: "memory")
#define WAITV0 asm volatile("s_waitcnt vmcnt(0)" ::: "memory")

// --- fused GEMM: 64x64 tile, 4 LDS buffers, 1 barrier/iter, counted vmcnt ---
// Full K per block (no split-K, no atomics). Epilogue fused.
__global__ __launch_bounds__(256, 4) void gemm_kernel(
    const u16* __restrict__ xb, const uint32_t* __restrict__ Tp,
    const float* __restrict__ alpha, const float* __restrict__ mu,
    const float* __restrict__ bias, const float* __restrict__ lora_B,
    const float* __restrict__ srow, const float* __restrict__ lxa,
    float* __restrict__ out)
{
    __shared__ __align__(16) u16 ldsA[4][BM * BK];       // 4 x 8 KB
    __shared__ __align__(16) uint32_t ldsB[4][BN * 4];   // 4 x 1 KB

    const int tid = threadIdx.x;
    const int lane = tid & 63;
    const int wave = tid >> 6;
    const int wm = wave >> 1, wn = wave & 1;
    const int mb = blockIdx.y * BM;
    const int nb = blockIdx.x * BN;

    const int bshift = ((lane >> 4) & 1) * 16;

    // A-stage: 512 x 16B chunks; 2 per thread; XOR-swizzled SOURCE, linear dest
    const u16* asrc[2];
    int adst[2];
#pragma unroll
    for (int j = 0; j < 2; ++j) {
        int q = j * 256 + tid;
        int row = q >> 3;            // 8 chunks per 64-elem row
        int scc = (q & 7) ^ (row & 7);
        asrc[j] = xb + (size_t)(mb + row) * IN_F + scc * 8;
        adst[j] = q * 8;             // u16 elements
    }
    // B-stage: 64 rows x 16B; every wave stages all 64 rows (duplicate writes,
    // keeps per-wave vmcnt uniform at 3 loads per stage)
    const uint32_t* bsrc = Tp + (size_t)(nb + lane) * NWORDS;
    const int bdst = lane * 4;       // u32 elements

    floatx4 acc[2][2] = {};

    auto stage = [&](int buf, int git) {
        const int k0 = git * BK;
#pragma unroll
        for (int j = 0; j < 2; ++j) {
            __builtin_amdgcn_global_load_lds(
                (const __attribute__((address_space(1))) void*)(asrc[j] + k0),
                (__attribute__((address_space(3))) void*)(&ldsA[buf][adst[j]]),
                16, 0, 0);
        }
        __builtin_amdgcn_global_load_lds(
            (const __attribute__((address_space(1))) void*)(bsrc + git * 4),
            (__attribute__((address_space(3))) void*)(&ldsB[buf][bdst]),
            16, 0, 0);
    };

    // body: top-of-iter vmcnt+barrier already done; stages into buf (j+3)&3,
    // which every wave finished reading at iter j-1 (proven by this barrier).
    auto body = [&](int buf, int buf_next, int git_next, bool do_stage) {
        if (do_stage) stage(buf_next, git_next);
        __builtin_amdgcn_sched_barrier(0);     // pin stage issue before compute
        short8 af[2][2];
        uint32_t bwd[2][2];
#pragma unroll
        for (int mt = 0; mt < 2; ++mt) {
            int r = wm * 32 + mt * 16 + (lane & 15);
#pragma unroll
            for (int kk = 0; kk < 2; ++kk) {
                int sc = kk * 4 + (lane >> 4);
                int chunk = r * 8 + (sc ^ (r & 7));
                af[mt][kk] = *(const short8*)&ldsA[buf][chunk * 8];
            }
        }
#pragma unroll
        for (int nt = 0; nt < 2; ++nt) {
            int row = wn * 32 + nt * 16 + (lane & 15);
#pragma unroll
            for (int kk = 0; kk < 2; ++kk)
                bwd[nt][kk] = ldsB[buf][row * 4 + kk * 2 + (lane >> 5)];
        }
        __builtin_amdgcn_s_setprio(1);
#pragma unroll
        for (int kk = 0; kk < 2; ++kk) {
            short8 bf[2];
#pragma unroll
            for (int nt = 0; nt < 2; ++nt)
                bf[nt] = decode8((bwd[nt][kk] >> bshift) & 0xFFFFu);
#pragma unroll
            for (int mt = 0; mt < 2; ++mt)
#pragma unroll
                for (int nt = 0; nt < 2; ++nt)
                    acc[mt][nt] = __builtin_amdgcn_mfma_f32_16x16x32_bf16(
                        af[mt][kk], bf[nt], acc[mt][nt], 0, 0, 0);
        }
        __builtin_amdgcn_s_setprio(0);
    };

    // prologue: fill 3 buffers (9 loads per thread in flight)
    stage(0, 0);
    stage(1, 1);
    stage(2, 2);

    // steady: iters 0..60 stage tile j+3 into buf (j+3)&3
    for (int j = 0; j <= NIT - 4; ++j) {
        WAITV6;                                // tile j landed; j+1, j+2 in flight
        __builtin_amdgcn_s_barrier();
        body(j & 3, (j + 3) & 3, j + 3, true);
    }
    // drain: iters 61, 62, 63
    WAITV6; __builtin_amdgcn_s_barrier();
    body((NIT - 3) & 3, 0, 0, false);
    WAITV3; __builtin_amdgcn_s_barrier();
    body((NIT - 2) & 3, 0, 0, false);
    WAITV0; __builtin_amdgcn_s_barrier();
    body((NIT - 1) & 3, 0, 0, false);

    // ---- fused epilogue: out = alpha*acc + mu*rowsum + 2*lora + bias ----
    const int o0 = nb + wn * 32 + (lane & 15);
    const int m0 = mb + wm * 32 + ((lane >> 4) * 4);

    float al[2], muv[2], bi[2], Brow[2][RANK];
#pragma unroll
    for (int nt = 0; nt < 2; ++nt) {
        int o = o0 + nt * 16;
        al[nt] = alpha[o];
        muv[nt] = mu[o];
        bi[nt] = bias[o];
        const float4* b4 = (const float4*)(lora_B + (size_t)o * RANK);
#pragma unroll
        for (int r4 = 0; r4 < RANK / 4; ++r4) {
            float4 v = b4[r4];
            Brow[nt][r4 * 4 + 0] = v.x; Brow[nt][r4 * 4 + 1] = v.y;
            Brow[nt][r4 * 4 + 2] = v.z; Brow[nt][r4 * 4 + 3] = v.w;
        }
    }
#pragma unroll
    for (int mt = 0; mt < 2; ++mt) {
#pragma unroll
        for (int rg = 0; rg < 4; ++rg) {
            int m = m0 + mt * 16 + rg;
            float sm = srow[m];
            float lx[RANK];
            const float4* l4 = (const float4*)(lxa + (size_t)m * RANK);
#pragma unroll
            for (int r4 = 0; r4 < RANK / 4; ++r4) {
                float4 v = l4[r4];
                lx[r4 * 4 + 0] = v.x; lx[r4 * 4 + 1] = v.y;
                lx[r4 * 4 + 2] = v.z; lx[r4 * 4 + 3] = v.w;
            }
#pragma unroll
            for (int nt = 0; nt < 2; ++nt) {
                float lora = 0.f;
#pragma unroll
                for (int r = 0; r < RANK; ++r) lora = fmaf(lx[r], Brow[nt][r], lora);
                out[(size_t)m * OUT_F + o0 + nt * 16] =
                    al[nt] * acc[mt][nt][rg] + muv[nt] * sm + 2.0f * lora + bi[nt];
            }
        }
    }
}

extern "C" void kernel_launch(void* const* d_in, const int* in_sizes, int n_in,
                              void* d_out, int out_size, void* d_ws, size_t ws_size,
                              hipStream_t stream)
{
    const float* x = (const float*)d_in[0];
    const uint32_t* Tp = (const uint32_t*)d_in[1];
    const float* alpha = (const float*)d_in[2];
    const float* mu = (const float*)d_in[3];
    const float* bias = (const float*)d_in[4];
    const float* lora_A = (const float*)d_in[5];
    const float* lora_B = (const float*)d_in[6];
    float* out = (float*)d_out;

    u16* xb = (u16*)d_ws;
    float* srow = (float*)((char*)d_ws + (size_t)M_ROWS * IN_F * 2);
    float* lxa = (float*)((char*)d_ws + (size_t)M_ROWS * IN_F * 2 + 4096);

    prep_kernel<<<dim3(M_ROWS), dim3(256), 0, stream>>>(x, lora_A, xb, srow, lxa);
    gemm_kernel<<<dim3(OUT_F / BN, M_ROWS / BM), dim3(256), 0, stream>>>(
        xb, Tp, alpha, mu, bias, lora_B, srow, lxa, out);
}

// Round 6
// 62.607 us; speedup vs baseline: 2.0607x; 1.2360x over previous
//
#include <hip/hip_runtime.h>
#include <stdint.h>

#define IN_F 4096
#define OUT_F 11008
#define M_ROWS 256
#define RANK 16
#define NWORDS (IN_F / 16)   // 256 packed words per output row

#define BM 64
#define BN 64
#define BK 64
#define NIT (IN_F / BK)      // 64 K-iterations, full K per block

typedef unsigned short u16;
typedef __attribute__((ext_vector_type(8))) short short8;
typedef __attribute__((ext_vector_type(4))) float floatx4;

__device__ __forceinline__ u16 f32_to_bf16_rne(float f) {
    uint32_t u = __builtin_bit_cast(uint32_t, f);
    uint32_t r = (u + 0x7FFFu + ((u >> 16) & 1u)) >> 16;
    return (u16)r;
}

// ---------------- prep: rowsum, lora_xA, x->bf16 (float4-vectorized) --------
__global__ __launch_bounds__(256) void prep_kernel(
    const float* __restrict__ x, const float* __restrict__ lora_A,
    u16* __restrict__ xb, float* __restrict__ srow, float* __restrict__ lxa)
{
    const int m = blockIdx.x;
    const int tid = threadIdx.x;
    const float4* xrow4 = (const float4*)(x + (size_t)m * IN_F);
    const float4* la4 = (const float4*)lora_A;
    float ssum = 0.f;
    float acc[RANK];
#pragma unroll
    for (int r = 0; r < RANK; ++r) acc[r] = 0.f;
#pragma unroll
    for (int t = 0; t < IN_F / (256 * 4); ++t) {
        int i4 = t * 256 + tid;
        float4 v = xrow4[i4];
        ssum += v.x + v.y + v.z + v.w;
        union { u16 h[4]; uint2 u2; } pk;
        pk.h[0] = f32_to_bf16_rne(v.x);
        pk.h[1] = f32_to_bf16_rne(v.y);
        pk.h[2] = f32_to_bf16_rne(v.z);
        pk.h[3] = f32_to_bf16_rne(v.w);
        *(uint2*)&xb[(size_t)m * IN_F + i4 * 4] = pk.u2;
#pragma unroll
        for (int r = 0; r < RANK; ++r) {
            float4 a = la4[r * (IN_F / 4) + i4];
            acc[r] = fmaf(v.x, a.x, fmaf(v.y, a.y, fmaf(v.z, a.z, fmaf(v.w, a.w, acc[r]))));
        }
    }
#pragma unroll
    for (int off = 32; off > 0; off >>= 1) {
        ssum += __shfl_down(ssum, off, 64);
#pragma unroll
        for (int r = 0; r < RANK; ++r) acc[r] += __shfl_down(acc[r], off, 64);
    }
    __shared__ float red[4][RANK + 1];
    int wv = tid >> 6, ln = tid & 63;
    if (ln == 0) {
        red[wv][0] = ssum;
#pragma unroll
        for (int r = 0; r < RANK; ++r) red[wv][1 + r] = acc[r];
    }
    __syncthreads();
    if (tid == 0) srow[m] = red[0][0] + red[1][0] + red[2][0] + red[3][0];
    if (tid < RANK)
        lxa[m * RANK + tid] = red[0][1 + tid] + red[1][1 + tid] + red[2][1 + tid] + red[3][1 + tid];
}

// ---------------- ternary decode: 8 x 2-bit codes -> 8 bf16 ----------------
// VERIFIED (R1/R2/R4/R5): OR-based spread, no carries.
// code c: 0 -> -1 (0xBF80), 1 -> 0 (0x0000), 2 -> +1 (0x3F80)
__device__ __forceinline__ short8 decode8(uint32_t h)
{
    uint32_t selA = (h & 0xFu) | ((h & 0xF0u) << 12);
    selA = (selA | (selA << 6)) & 0x03030303u;
    uint32_t h2 = h >> 8;
    uint32_t selB = (h2 & 0xFu) | ((h2 & 0xF0u) << 12);
    selB = (selB | (selB << 6)) & 0x03030303u;
    uint32_t hiA = __builtin_amdgcn_perm(0u, 0x003F00BFu, selA);
    uint32_t loA = __builtin_amdgcn_perm(0u, 0x00800080u, selA);
    uint32_t hiB = __builtin_amdgcn_perm(0u, 0x003F00BFu, selB);
    uint32_t loB = __builtin_amdgcn_perm(0u, 0x00800080u, selB);
    union { uint32_t u[4]; short8 s; } cvt;
    cvt.u[0] = __builtin_amdgcn_perm(hiA, loA, 0x05010400u);
    cvt.u[1] = __builtin_amdgcn_perm(hiA, loA, 0x07030602u);
    cvt.u[2] = __builtin_amdgcn_perm(hiB, loB, 0x05010400u);
    cvt.u[3] = __builtin_amdgcn_perm(hiB, loB, 0x07030602u);
    return cvt.s;
}

#define WAITV6 asm volatile("s_waitcnt vmcnt(6)" ::: "memory")
#define WAITV3 asm volatile("s_waitcnt vmcnt(3)" ::: "memory")
#define WAITV0 asm volatile("s_waitcnt vmcnt(0)" ::: "memory")
#define BAR    __builtin_amdgcn_s_barrier()
#define SCHED0 __builtin_amdgcn_sched_barrier(0)

struct Frags {
    short8 af[2][2];
    uint32_t bwd[2][2];
};

// --- fused GEMM: 64x64 tile, 4 LDS buffers, reg-pipelined fragments ---
// Per iter j: stage(j+3) | compute(j) on regs read last iter | vmcnt(6)
// | barrier | read frags(j+1). LDS latency hides under MFMA + barrier.
__global__ __launch_bounds__(256, 4) void gemm_kernel(
    const u16* __restrict__ xb, const uint32_t* __restrict__ Tp,
    const float* __restrict__ alpha, const float* __restrict__ mu,
    const float* __restrict__ bias, const float* __restrict__ lora_B,
    const float* __restrict__ srow, const float* __restrict__ lxa,
    float* __restrict__ out)
{
    __shared__ __align__(16) u16 ldsA[4][BM * BK];       // 4 x 8 KB
    __shared__ __align__(16) uint32_t ldsB[4][BN * 4];   // 4 x 1 KB

    const int tid = threadIdx.x;
    const int lane = tid & 63;
    const int wave = tid >> 6;
    const int wm = wave >> 1, wn = wave & 1;
    const int mb = blockIdx.y * BM;
    const int nb = blockIdx.x * BN;

    const int bshift = ((lane >> 4) & 1) * 16;

    // A-stage: 512 x 16B chunks; 2 per thread; XOR-swizzled SOURCE, linear dest
    const u16* asrc[2];
    int adst[2];
#pragma unroll
    for (int j = 0; j < 2; ++j) {
        int q = j * 256 + tid;
        int row = q >> 3;            // 8 chunks per 64-elem row
        int scc = (q & 7) ^ (row & 7);
        asrc[j] = xb + (size_t)(mb + row) * IN_F + scc * 8;
        adst[j] = q * 8;             // u16 elements
    }
    // B-stage: 64 rows x 16B; every wave stages all 64 rows (duplicate writes,
    // keeps per-wave vmcnt uniform at 3 loads per stage)
    const uint32_t* bsrc = Tp + (size_t)(nb + lane) * NWORDS;
    const int bdst = lane * 4;       // u32 elements

    // precomputed per-thread fragment offsets (compile-time indexed)
    int aoff[2][2], boff[2][2];
#pragma unroll
    for (int mt = 0; mt < 2; ++mt)
#pragma unroll
        for (int kk = 0; kk < 2; ++kk) {
            int r = wm * 32 + mt * 16 + (lane & 15);
            int sc = kk * 4 + (lane >> 4);
            aoff[mt][kk] = (r * 8 + (sc ^ (r & 7))) * 8;   // u16 units
        }
#pragma unroll
    for (int nt = 0; nt < 2; ++nt)
#pragma unroll
        for (int kk = 0; kk < 2; ++kk) {
            int row = wn * 32 + nt * 16 + (lane & 15);
            boff[nt][kk] = row * 4 + kk * 2 + (lane >> 5);
        }

    floatx4 acc[2][2] = {};

    auto stage = [&](int buf, int git) {
        const int k0 = git * BK;
#pragma unroll
        for (int j = 0; j < 2; ++j) {
            __builtin_amdgcn_global_load_lds(
                (const __attribute__((address_space(1))) void*)(asrc[j] + k0),
                (__attribute__((address_space(3))) void*)(&ldsA[buf][adst[j]]),
                16, 0, 0);
        }
        __builtin_amdgcn_global_load_lds(
            (const __attribute__((address_space(1))) void*)(bsrc + git * 4),
            (__attribute__((address_space(3))) void*)(&ldsB[buf][bdst]),
            16, 0, 0);
    };

    auto rdfrags = [&](int buf, Frags& F) {
#pragma unroll
        for (int mt = 0; mt < 2; ++mt)
#pragma unroll
            for (int kk = 0; kk < 2; ++kk)
                F.af[mt][kk] = *(const short8*)&ldsA[buf][aoff[mt][kk]];
#pragma unroll
        for (int nt = 0; nt < 2; ++nt)
#pragma unroll
            for (int kk = 0; kk < 2; ++kk)
                F.bwd[nt][kk] = ldsB[buf][boff[nt][kk]];
    };

    auto compute = [&](Frags& F) {
        __builtin_amdgcn_s_setprio(1);
#pragma unroll
        for (int kk = 0; kk < 2; ++kk) {
            short8 bf[2];
#pragma unroll
            for (int nt = 0; nt < 2; ++nt)
                bf[nt] = decode8((F.bwd[nt][kk] >> bshift) & 0xFFFFu);
#pragma unroll
            for (int mt = 0; mt < 2; ++mt)
#pragma unroll
                for (int nt = 0; nt < 2; ++nt)
                    acc[mt][nt] = __builtin_amdgcn_mfma_f32_16x16x32_bf16(
                        F.af[mt][kk], bf[nt], acc[mt][nt], 0, 0, 0);
        }
        __builtin_amdgcn_s_setprio(0);
    };

    Frags fA, fB;

    // prologue: fill 3 buffers; read frags(0)
    stage(0, 0);
    stage(1, 1);
    stage(2, 2);
    WAITV6; BAR;                 // tile 0 landed for all waves
    rdfrags(0, fA); SCHED0;

    // steady: j = 0..59, unrolled x4 (buffer index compile-time)
    for (int u = 0; u < 15; ++u) {
        const int jb = u * 4;
        stage(3, jb + 3); SCHED0; compute(fA); WAITV6; BAR; rdfrags(1, fB); SCHED0;
        stage(0, jb + 4); SCHED0; compute(fB); WAITV6; BAR; rdfrags(2, fA); SCHED0;
        stage(1, jb + 5); SCHED0; compute(fA); WAITV6; BAR; rdfrags(3, fB); SCHED0;
        stage(2, jb + 6); SCHED0; compute(fB); WAITV6; BAR; rdfrags(0, fA); SCHED0;
    }
    // j = 60 (stages last tile 63), then drain 61/62/63
    stage(3, 63); SCHED0; compute(fA); WAITV6; BAR; rdfrags(1, fB); SCHED0;
    compute(fB); WAITV3; BAR; rdfrags(2, fA); SCHED0;   // j = 61
    compute(fA); WAITV0; BAR; rdfrags(3, fB); SCHED0;   // j = 62
    compute(fB);                                        // j = 63

    // ---- fused epilogue: out = alpha*acc + mu*rowsum + 2*lora + bias ----
    const int o0 = nb + wn * 32 + (lane & 15);
    const int m0 = mb + wm * 32 + ((lane >> 4) * 4);

    float al[2], muv[2], bi[2], Brow[2][RANK];
#pragma unroll
    for (int nt = 0; nt < 2; ++nt) {
        int o = o0 + nt * 16;
        al[nt] = alpha[o];
        muv[nt] = mu[o];
        bi[nt] = bias[o];
        const float4* b4 = (const float4*)(lora_B + (size_t)o * RANK);
#pragma unroll
        for (int r4 = 0; r4 < RANK / 4; ++r4) {
            float4 v = b4[r4];
            Brow[nt][r4 * 4 + 0] = v.x; Brow[nt][r4 * 4 + 1] = v.y;
            Brow[nt][r4 * 4 + 2] = v.z; Brow[nt][r4 * 4 + 3] = v.w;
        }
    }
#pragma unroll
    for (int mt = 0; mt < 2; ++mt) {
#pragma unroll
        for (int rg = 0; rg < 4; ++rg) {
            int m = m0 + mt * 16 + rg;
            float sm = srow[m];
            float lx[RANK];
            const float4* l4 = (const float4*)(lxa + (size_t)m * RANK);
#pragma unroll
            for (int r4 = 0; r4 < RANK / 4; ++r4) {
                float4 v = l4[r4];
                lx[r4 * 4 + 0] = v.x; lx[r4 * 4 + 1] = v.y;
                lx[r4 * 4 + 2] = v.z; lx[r4 * 4 + 3] = v.w;
            }
#pragma unroll
            for (int nt = 0; nt < 2; ++nt) {
                float lora = 0.f;
#pragma unroll
                for (int r = 0; r < RANK; ++r) lora = fmaf(lx[r], Brow[nt][r], lora);
                out[(size_t)m * OUT_F + o0 + nt * 16] =
                    al[nt] * acc[mt][nt][rg] + muv[nt] * sm + 2.0f * lora + bi[nt];
            }
        }
    }
}

extern "C" void kernel_launch(void* const* d_in, const int* in_sizes, int n_in,
                              void* d_out, int out_size, void* d_ws, size_t ws_size,
                              hipStream_t stream)
{
    const float* x = (const float*)d_in[0];
    const uint32_t* Tp = (const uint32_t*)d_in[1];
    const float* alpha = (const float*)d_in[2];
    const float* mu = (const float*)d_in[3];
    const float* bias = (const float*)d_in[4];
    const float* lora_A = (const float*)d_in[5];
    const float* lora_B = (const float*)d_in[6];
    float* out = (float*)d_out;

    u16* xb = (u16*)d_ws;
    float* srow = (float*)((char*)d_ws + (size_t)M_ROWS * IN_F * 2);
    float* lxa = (float*)((char*)d_ws + (size_t)M_ROWS * IN_F * 2 + 4096);

    prep_kernel<<<dim3(M_ROWS), dim3(256), 0, stream>>>(x, lora_A, xb, srow, lxa);
    gemm_kernel<<<dim3(OUT_F / BN, M_ROWS / BM), dim3(256), 0, stream>>>(
        xb, Tp, alpha, mu, bias, lora_B, srow, lxa, out);
}